// Round 5
// baseline (69.671 us; speedup 1.0000x reference)
//
#include <hip/hip_runtime.h>
#include <cmath>

// NALU forward: B=8192, D=U=128.
// out = g1*a1 + (1-g1)*parity*exp(min(mlog,20)+slog)
//   a1   = x @ w1
//   mlog = log(max(|x|,1e-7)) @ w2
//   slog = (x<0) @ log|1-2*|w2^T||   (sign path in log space)
//   cnt  = (x<0) @ [1-2*|w2^T| < 0]  (parity of negative factors)
// R4 (69.5us) + occupancy fix: main now 512 blocks x 16 rows -> 2 blocks/CU
// so one block's staging/convert overlaps the other's MFMA/epilogue
// (R4 ran 1 block/CU, fully latency-exposed critical path).

typedef __bf16  bf16x8 __attribute__((ext_vector_type(8)));
typedef float   f32x4  __attribute__((ext_vector_type(4)));

__device__ __forceinline__ unsigned short f2bf(float f) {
    union { float f; unsigned int u; } v; v.f = f;
    unsigned int u = v.u;
    unsigned int r = (u + 0x7FFFu + ((u >> 16) & 1u)) >> 16;   // RNE
    return (unsigned short)r;
}
__device__ __forceinline__ unsigned int pck(unsigned short a, unsigned short b) {
    return (unsigned int)a | ((unsigned int)b << 16);
}
__device__ __forceinline__ float fast_sig(float v) {
    return 1.0f / (1.0f + __expf(-v));          // v_exp_f32 path
}
__device__ __forceinline__ float fast_tanh(float v) {
    return 1.0f - 2.0f / (1.0f + __expf(2.0f * v));
}

// MFMA B-fragment linear offset for value Bmat[k][n] in the full 128-col
// matrix: [nblk(8)][kstep(4)][lane=quad*16+l16][j(8)], quad=(k>>3)&3.
__device__ __forceinline__ int fragaddr(int n, int k) {
    int nblk = n >> 4, l16 = n & 15, kstep = k >> 5, quad = (k >> 3) & 3, j = k & 7;
    return (((nblk * 4 + kstep) * 64 + quad * 16 + l16) * 8) + j;
}

// ---------------------------------------------------------------------------
// Prep: 4 derived weight matrices in bf16, MFMA B-fragment order.
// Thread handles element (d,u) with u fast-varying -> ALL 4 loads coalesced.
// S/neg for the transposed slot (k=u, n=d) are functions of w2[d][u].
// ---------------------------------------------------------------------------
__global__ void nalu_prep(const float* __restrict__ w_hat,
                          const float* __restrict__ m_hat,
                          const float* __restrict__ whp,
                          const float* __restrict__ mhp,
                          unsigned short* __restrict__ Bsw) {
    int i = blockIdx.x * 256 + threadIdx.x;   // 0..16383
    int d = i >> 7;      // reduction index
    int u = i & 127;     // output column (fast -> coalesced)
    int dk = d * 128 + u;

    float w1v = fast_tanh(w_hat[dk]) * fast_sig(m_hat[dk]);
    float w2v = fast_tanh(whp[dk])   * fast_sig(mhp[dk]);
    float f   = 1.0f - 2.0f * fabsf(w2v);
    float Sv  = fmaxf(__logf(fmaxf(fabsf(f), 1e-38f)), -80.0f);
    float ngv = (f < 0.0f) ? 1.0f : 0.0f;

    const int MS = 16384;
    Bsw[fragaddr(u, d)]          = f2bf(w1v);   // w1[k=d][n=u]
    Bsw[fragaddr(u, d) + MS]     = f2bf(w2v);   // w2[k=d][n=u]
    Bsw[fragaddr(d, u) + 2 * MS] = f2bf(Sv);    // S[k=u][n=d] = f(w2[d][u])
    Bsw[fragaddr(d, u) + 3 * MS] = f2bf(ngv);   // neg[k=u][n=d]
}

// ---------------------------------------------------------------------------
// Main: 512 blocks x 256 threads, 2 blocks/CU. Block = 16 rows x 128 cols.
// Wave w: all 16 rows (1 msub), cols [w*32, +32) (2 nsub of 16).
// A staged in LDS as [mat][m 16][k 136] bf16 (~13 KB -> occupancy-friendly).
// ---------------------------------------------------------------------------
__global__ __launch_bounds__(256, 2)
void nalu_main(const float* __restrict__ x,
               const unsigned short* __restrict__ Bsw,
               const float* __restrict__ g,
               float* __restrict__ out) {
    __shared__ __align__(16) unsigned short As[3][16][136];

    const int t    = threadIdx.x;
    const int wave = t >> 6;
    const int lane = t & 63;
    const int quad = lane >> 4;
    const int l16  = lane & 15;
    const int rowblk = blockIdx.x * 16;

    // --- Issue all B-fragment loads up front (coalesced dwordx4, L2-hot) ---
    bf16x8 Bf[4][2][4];   // [mat][nsub][kstep]
    const bf16x8* Bp = reinterpret_cast<const bf16x8*>(Bsw);
    #pragma unroll
    for (int mat = 0; mat < 4; ++mat)
        #pragma unroll
        for (int ns = 0; ns < 2; ++ns)
            #pragma unroll
            for (int ks = 0; ks < 4; ++ks) {
                int nblk = wave * 2 + ns;
                Bf[mat][ns][ks] = Bp[((mat * 8 + nblk) * 4 + ks) * 64 + lane];
            }

    // --- Stage A matrices (x, log|x|, x<0) into LDS as bf16 ---
    const float4* xv = reinterpret_cast<const float4*>(x + rowblk * 128);
    #pragma unroll
    for (int it = 0; it < 2; ++it) {
        int idx  = t + it * 256;      // 0..511 = 16 rows x 32 float4
        int row  = idx >> 5;
        int col4 = idx & 31;
        float4 v = xv[idx];
        float vv[4] = {v.x, v.y, v.z, v.w};
        unsigned short sx[4], sl[4], sn[4];
        #pragma unroll
        for (int j = 0; j < 4; ++j) {
            float f = vv[j];
            sx[j] = f2bf(f);
            sl[j] = f2bf(__logf(fmaxf(fabsf(f), 1e-7f)));
            sn[j] = (f < 0.0f) ? (unsigned short)0x3F80u : (unsigned short)0u;
        }
        uint2 px = {pck(sx[0], sx[1]), pck(sx[2], sx[3])};
        uint2 pl = {pck(sl[0], sl[1]), pck(sl[2], sl[3])};
        uint2 pn = {pck(sn[0], sn[1]), pck(sn[2], sn[3])};
        *reinterpret_cast<uint2*>(&As[0][row][col4 * 4]) = px;
        *reinterpret_cast<uint2*>(&As[1][row][col4 * 4]) = pl;
        *reinterpret_cast<uint2*>(&As[2][row][col4 * 4]) = pn;
    }
    __syncthreads();

    // --- Accumulators: 4 chains x 2 nsub ---
    f32x4 accA[2], accM[2], accS[2], accC[2];
    #pragma unroll
    for (int ns = 0; ns < 2; ++ns) {
        f32x4 z = {0.0f, 0.0f, 0.0f, 0.0f};
        accA[ns] = z; accM[ns] = z; accS[ns] = z; accC[ns] = z;
    }

    // --- K loop: 4 ksteps of 32, fully unrolled ---
    #pragma unroll
    for (int ks = 0; ks < 4; ++ks) {
        int k = ks * 32 + quad * 8;
        bf16x8 Ax = *reinterpret_cast<const bf16x8*>(&As[0][l16][k]);
        bf16x8 Al = *reinterpret_cast<const bf16x8*>(&As[1][l16][k]);
        bf16x8 An = *reinterpret_cast<const bf16x8*>(&As[2][l16][k]);
        #pragma unroll
        for (int ns = 0; ns < 2; ++ns) {
            accA[ns] = __builtin_amdgcn_mfma_f32_16x16x32_bf16(Ax, Bf[0][ns][ks], accA[ns], 0, 0, 0);
            accM[ns] = __builtin_amdgcn_mfma_f32_16x16x32_bf16(Al, Bf[1][ns][ks], accM[ns], 0, 0, 0);
            accS[ns] = __builtin_amdgcn_mfma_f32_16x16x32_bf16(An, Bf[2][ns][ks], accS[ns], 0, 0, 0);
            accC[ns] = __builtin_amdgcn_mfma_f32_16x16x32_bf16(An, Bf[3][ns][ks], accC[ns], 0, 0, 0);
        }
    }

    // --- Epilogue: C/D layout col=lane&15, row=quad*4+reg ---
    #pragma unroll
    for (int ns = 0; ns < 2; ++ns) {
        int u = wave * 32 + ns * 16 + l16;
        float g1 = fast_sig(g[u]);
        float om = 1.0f - g1;
        int rbase = rowblk + quad * 4;
        #pragma unroll
        for (int r = 0; r < 4; ++r) {
            float a1 = accA[ns][r];
            float ml = accM[ns][r];
            float sl = accS[ns][r];
            float cn = accC[ns][r];   // exact integer count
            float par = 1.0f - 2.0f * (cn - 2.0f * floorf(cn * 0.5f));
            float mterm = par * __expf(fminf(ml, 20.0f) + sl);
            out[(rbase + r) * 128 + u] = g1 * a1 + om * mterm;
        }
    }
}

extern "C" void kernel_launch(void* const* d_in, const int* in_sizes, int n_in,
                              void* d_out, int out_size, void* d_ws, size_t ws_size,
                              hipStream_t stream) {
    const float* x     = (const float*)d_in[0];
    const float* w_hat = (const float*)d_in[1];
    const float* m_hat = (const float*)d_in[2];
    const float* whp   = (const float*)d_in[3];
    const float* mhp   = (const float*)d_in[4];
    const float* g     = (const float*)d_in[5];
    unsigned short* Bsw = (unsigned short*)d_ws;   // 4*16384*2 = 128 KiB
    float* outp = (float*)d_out;

    nalu_prep<<<64, 256, 0, stream>>>(w_hat, m_hat, whp, mhp, Bsw);
    nalu_main<<<512, 256, 0, stream>>>(x, Bsw, g, outp);
}